// Round 1
// baseline (395.917 us; speedup 1.0000x reference)
//
#include <hip/hip_runtime.h>
#include <math.h>

#define TT 16
#define HH 64
#define WW 64
#define CC 128
#define PLANE (HH*WW*CC)      // 524288 elements per t-slice
#define TOTALC (TT*PLANE)     // 8388608

__device__ __forceinline__ float2 cmul(float2 a, float2 b) {
    return make_float2(a.x*b.x - a.y*b.y, a.x*b.y + a.y*b.x);
}
// acc += a*b (complex)
__device__ __forceinline__ float2 cmac(float2 acc, float2 a, float2 b) {
    acc.x = fmaf(a.x, b.x, fmaf(-a.y, b.y, acc.x));
    acc.y = fmaf(a.x, b.y, fmaf(a.y, b.x, acc.y));
    return acc;
}

// ---------------- kernel preprocessing ----------------

__global__ __launch_bounds__(256) void k0_tanh(const float* __restrict__ a,
                                               float* __restrict__ as, int n) {
    int i = blockIdx.x * 256 + threadIdx.x;
    if (i < n) as[i] = 0.9f * tanhf(a[i]);
}

// DFT over kw (7 taps, offsets kw-3) -> Aw/Bw[kt][kh][omega][c]
__global__ __launch_bounds__(256) void k1a(const float* __restrict__ As,
                                           const float* __restrict__ Bk,
                                           float2* __restrict__ Aw,
                                           float2* __restrict__ Bw) {
    __shared__ float2 tw[64];
    for (int i = threadIdx.x; i < 64; i += 256) {
        float s, c; sincosf(-6.283185307179586f * i / 64.0f, &s, &c);
        tw[i] = make_float2(c, s);
    }
    __syncthreads();
    int i = blockIdx.x * 256 + threadIdx.x;   // 172032 total
    int c = i & 127;
    int om = (i >> 7) & 63;
    int rem = i >> 13;          // 0..20
    int kh = rem % 7, kt = rem / 7;
    int base = ((c * 3 + kt) * 7 + kh) * 7;
    float2 accA = make_float2(0.f, 0.f), accB = make_float2(0.f, 0.f);
    #pragma unroll
    for (int kw = 0; kw < 7; ++kw) {
        float2 t = tw[(om * (kw - 3)) & 63];
        float va = As[base + kw], vb = Bk[base + kw];
        accA.x = fmaf(va, t.x, accA.x); accA.y = fmaf(va, t.y, accA.y);
        accB.x = fmaf(vb, t.x, accB.x); accB.y = fmaf(vb, t.y, accB.y);
    }
    int o = ((kt * 7 + kh) * 64 + om) * 128 + c;
    Aw[o] = accA; Bw[o] = accB;
}

// DFT over kh (7 taps, offsets kh-3) -> Ahw/Bhw[kt][eta][omega][c]
__global__ __launch_bounds__(256) void k1b(const float2* __restrict__ Aw,
                                           const float2* __restrict__ Bw,
                                           float2* __restrict__ Ahw,
                                           float2* __restrict__ Bhw) {
    __shared__ float2 tw[64];
    for (int i = threadIdx.x; i < 64; i += 256) {
        float s, c; sincosf(-6.283185307179586f * i / 64.0f, &s, &c);
        tw[i] = make_float2(c, s);
    }
    __syncthreads();
    int i = blockIdx.x * 256 + threadIdx.x;   // 1572864 total
    int c = i & 127, om = (i >> 7) & 63, eta = (i >> 13) & 63, kt = i >> 19;
    float2 accA = make_float2(0.f, 0.f), accB = make_float2(0.f, 0.f);
    #pragma unroll
    for (int kh = 0; kh < 7; ++kh) {
        float2 t = tw[(eta * (kh - 3)) & 63];
        int s = ((kt * 7 + kh) * 64 + om) * 128 + c;
        accA = cmac(accA, Aw[s], t);
        accB = cmac(accB, Bw[s], t);
    }
    int o = ((kt * 64 + eta) * 64 + om) * 128 + c;
    Ahw[o] = accA; Bhw[o] = accB;
}

// ---------------- pass 1: forward DFT along W (real -> complex) ----------------
__global__ __launch_bounds__(256) void p1(const float* __restrict__ x,
                                          float2* __restrict__ out) {
    __shared__ float tile[WW][CC];       // 32 KB
    __shared__ float2 tw[64];
    int t = blockIdx.x >> 6, h = blockIdx.x & 63;
    for (int i = threadIdx.x; i < 64; i += 256) {
        float s, c; sincosf(-6.283185307179586f * i / 64.0f, &s, &c);
        tw[i] = make_float2(c, s);
    }
    const float* src = x + (size_t)(t * HH + h) * WW * CC;
    for (int i = threadIdx.x; i < WW * CC; i += 256) tile[i >> 7][i & 127] = src[i];
    __syncthreads();
    int c = threadIdx.x & 127;
    int wb = threadIdx.x >> 7;           // 0 or 1
    float2 acc[32];
    #pragma unroll
    for (int k = 0; k < 32; ++k) acc[k] = make_float2(0.f, 0.f);
    for (int w = 0; w < WW; ++w) {
        float v = tile[w][c];
        int idx = (wb * w) & 63;
        int step = (2 * w) & 63;
        #pragma unroll
        for (int k = 0; k < 32; ++k) {
            float2 tt = tw[idx];
            acc[k].x = fmaf(v, tt.x, acc[k].x);
            acc[k].y = fmaf(v, tt.y, acc[k].y);
            idx = (idx + step) & 63;
        }
    }
    float2* dst = out + (size_t)(t * HH + h) * WW * CC;
    #pragma unroll
    for (int k = 0; k < 32; ++k) {
        int om = wb + 2 * k;
        dst[om * CC + c] = acc[k];
    }
}

// ---------------- pass 2/4: DFT along H, in place. SIGN=-1 fwd, +1 inv ----------------
template<int SIGN>
__global__ __launch_bounds__(256) void p2(float2* __restrict__ buf) {
    __shared__ float2 tile[HH][64];      // 32 KB
    __shared__ float2 tw[64];
    int bid = blockIdx.x;
    int chalf = bid & 1, om = (bid >> 1) & 63, t = bid >> 7;
    for (int i = threadIdx.x; i < 64; i += 256) {
        float s, c; sincosf((float)SIGN * 6.283185307179586f * i / 64.0f, &s, &c);
        tw[i] = make_float2(c, s);
    }
    float2* base = buf + (size_t)t * PLANE + om * CC + chalf * 64;
    for (int i = threadIdx.x; i < HH * 64; i += 256) {
        int h = i >> 6, c = i & 63;
        tile[h][c] = base[(size_t)h * WW * CC + c];
    }
    __syncthreads();
    int c = threadIdx.x & 63;
    int kb = threadIdx.x >> 6;           // 0..3
    float2 acc[16];
    #pragma unroll
    for (int k = 0; k < 16; ++k) acc[k] = make_float2(0.f, 0.f);
    for (int h = 0; h < HH; ++h) {
        float2 v = tile[h][c];
        int idx = (kb * h) & 63;
        int step = (4 * h) & 63;
        #pragma unroll
        for (int k = 0; k < 16; ++k) {
            acc[k] = cmac(acc[k], v, tw[idx]);
            idx = (idx + step) & 63;
        }
    }
    #pragma unroll
    for (int k = 0; k < 16; ++k) {
        int kh = kb + 4 * k;
        base[(size_t)kh * WW * CC + c] = acc[k];
    }
}

// ------- pass 3: fwd 16-pt DFT along T + G(tau)=S(A_f)B_f multiply + inv DFT, in place -------
__global__ __launch_bounds__(128) void p3(float2* __restrict__ buf,
                                          const float2* __restrict__ Ahw,
                                          const float2* __restrict__ Bhw) {
    __shared__ float2 tw[16];
    if (threadIdx.x < 16) {
        float s, c; sincosf(-6.283185307179586f * threadIdx.x / 16.0f, &s, &c);
        tw[threadIdx.x] = make_float2(c, s);
    }
    __syncthreads();
    int eta = blockIdx.x >> 6, om = blockIdx.x & 63;
    int c = threadIdx.x;
    size_t base = (size_t)(eta * WW + om) * CC + c;
    float2 v[16];
    #pragma unroll
    for (int t = 0; t < 16; ++t) v[t] = buf[(size_t)t * PLANE + base];
    // forward DFT along t
    float2 X[16];
    #pragma unroll
    for (int ta = 0; ta < 16; ++ta) {
        float2 a = make_float2(0.f, 0.f);
        #pragma unroll
        for (int t = 0; t < 16; ++t) a = cmac(a, v[t], tw[(ta * t) & 15]);
        X[ta] = a;
    }
    // per-tau kernel response
    int kb = (eta * 64 + om) * 128 + c;
    float2 A0 = Ahw[kb], A1 = Ahw[kb + 524288], A2 = Ahw[kb + 1048576];
    float2 B0 = Bhw[kb], B1 = Bhw[kb + 524288], B2 = Bhw[kb + 1048576];
    #pragma unroll
    for (int ta = 0; ta < 16; ++ta) {
        float2 wv = tw[ta];
        float2 wc = make_float2(wv.x, -wv.y);
        // A_f = Ahw1 + conj(w)*Ahw0 + w*Ahw2   (kt offsets -1,0,+1; fwd twiddle e^{-2pi i tau (kt-1)/16})
        float2 Af = A1; Af = cmac(Af, A0, wc); Af = cmac(Af, A2, wv);
        float2 Bf = B1; Bf = cmac(Bf, B0, wc); Bf = cmac(Bf, B2, wv);
        // S = sum_{k=0}^{7} Af^k  via Horner
        float2 S = make_float2(1.f, 0.f);
        #pragma unroll
        for (int k = 0; k < 7; ++k) {
            float2 t2 = cmul(Af, S);
            S = make_float2(1.f + t2.x, t2.y);
        }
        float2 G = cmul(S, Bf);
        X[ta] = cmul(X[ta], G);
    }
    // inverse DFT along t (unnormalized; global 1/65536 applied in p5)
    #pragma unroll
    for (int t = 0; t < 16; ++t) {
        float2 a = make_float2(0.f, 0.f);
        #pragma unroll
        for (int ta = 0; ta < 16; ++ta) {
            float2 wv = tw[(ta * t) & 15];
            float2 wc = make_float2(wv.x, -wv.y);
            a = cmac(a, X[ta], wc);
        }
        buf[(size_t)t * PLANE + base] = a;
    }
}

// ---------------- pass 5: inverse DFT along W, real part, scale ----------------
__global__ __launch_bounds__(256) void p5(const float2* __restrict__ buf,
                                          float* __restrict__ out) {
    __shared__ float2 tile[WW][64];      // 32 KB
    __shared__ float2 tw[64];
    int bid = blockIdx.x;
    int chalf = bid & 1, h = (bid >> 1) & 63, t = bid >> 7;
    for (int i = threadIdx.x; i < 64; i += 256) {
        float s, c; sincosf(6.283185307179586f * i / 64.0f, &s, &c);
        tw[i] = make_float2(c, s);
    }
    const float2* src = buf + (size_t)(t * HH + h) * WW * CC + chalf * 64;
    for (int i = threadIdx.x; i < WW * 64; i += 256) {
        int om = i >> 6, c = i & 63;
        tile[om][c] = src[om * CC + c];
    }
    __syncthreads();
    int c = threadIdx.x & 63;
    int wb = threadIdx.x >> 6;           // 0..3
    float acc[16];
    #pragma unroll
    for (int k = 0; k < 16; ++k) acc[k] = 0.f;
    for (int om = 0; om < 64; ++om) {
        float2 v = tile[om][c];
        int idx = (wb * om) & 63;
        int step = (4 * om) & 63;
        #pragma unroll
        for (int k = 0; k < 16; ++k) {
            float2 tt = tw[idx];
            acc[k] = fmaf(v.x, tt.x, fmaf(-v.y, tt.y, acc[k]));
            idx = (idx + step) & 63;
        }
    }
    float* dst = out + (size_t)(t * HH + h) * WW * CC + chalf * 64;
    #pragma unroll
    for (int k = 0; k < 16; ++k)
        dst[(wb + 4 * k) * CC + c] = acc[k] * (1.0f / 65536.0f);
}

extern "C" void kernel_launch(void* const* d_in, const int* in_sizes, int n_in,
                              void* d_out, int out_size, void* d_ws, size_t ws_size,
                              hipStream_t stream) {
    const float* x  = (const float*)d_in[0];
    const float* Ak = (const float*)d_in[1];
    const float* Bk = (const float*)d_in[2];
    float* out = (float*)d_out;

    // workspace layout (all float2 unless noted):
    //   buf   : 8388608        (67.1 MB)  main complex ping buffer (in-place passes)
    //   Ahw   : 3*64*64*128    (12.6 MB)
    //   Bhw   : 3*64*64*128    (12.6 MB)
    //   Aw    : 3*7*64*128     ( 1.4 MB)
    //   Bw    : 3*7*64*128     ( 1.4 MB)
    //   As    : 18816 floats   (75 KB)    tanh-stabilized A kernel
    float2* buf = (float2*)d_ws;
    float2* Ahw = buf + TOTALC;
    float2* Bhw = Ahw + 3 * 64 * 64 * 128;
    float2* Aw  = Bhw + 3 * 64 * 64 * 128;
    float2* Bw  = Aw + 3 * 7 * 64 * 128;
    float*  As  = (float*)(Bw + 3 * 7 * 64 * 128);

    hipLaunchKernelGGL(k0_tanh, dim3(74),   dim3(256), 0, stream, Ak, As, 18816);
    hipLaunchKernelGGL(k1a,     dim3(672),  dim3(256), 0, stream, As, Bk, Aw, Bw);
    hipLaunchKernelGGL(k1b,     dim3(6144), dim3(256), 0, stream, Aw, Bw, Ahw, Bhw);
    hipLaunchKernelGGL(p1,      dim3(1024), dim3(256), 0, stream, x, buf);
    hipLaunchKernelGGL(p2<-1>,  dim3(2048), dim3(256), 0, stream, buf);
    hipLaunchKernelGGL(p3,      dim3(4096), dim3(128), 0, stream, buf, Ahw, Bhw);
    hipLaunchKernelGGL(p2<1>,   dim3(2048), dim3(256), 0, stream, buf);
    hipLaunchKernelGGL(p5,      dim3(2048), dim3(256), 0, stream, buf, out);
}

// Round 2
// 151.226 us; speedup vs baseline: 2.6181x; 2.6181x over previous
//
#include <hip/hip_runtime.h>
#include <math.h>

#define TT 16
#define HH 64
#define WW 64
#define CC 128
#define PLANE (HH*WW*CC)      // 524288 float2 per t-slice
#define TOTALC (TT*PLANE)     // 8388608

__device__ __forceinline__ float2 cadd(float2 a, float2 b){ return make_float2(a.x+b.x, a.y+b.y); }
__device__ __forceinline__ float2 csub(float2 a, float2 b){ return make_float2(a.x-b.x, a.y-b.y); }
__device__ __forceinline__ float2 cmul(float2 a, float2 b) {
    return make_float2(a.x*b.x - a.y*b.y, a.x*b.y + a.y*b.x);
}
__device__ __forceinline__ float2 cmac(float2 acc, float2 a, float2 b) {
    acc.x = fmaf(a.x, b.x, fmaf(-a.y, b.y, acc.x));
    acc.y = fmaf(a.x, b.y, fmaf(a.y, b.x, acc.y));
    return acc;
}

// ---------------- radix butterflies ----------------
// DFT with twiddle e^{SGN*2pi i nk/N}; SGN=-1 forward, +1 inverse (unnormalized)

template<int SGN>
__device__ __forceinline__ void dft4(float2 b0, float2 b1, float2 b2, float2 b3,
                                     float2& y0, float2& y1, float2& y2, float2& y3) {
    float2 e0 = cadd(b0, b2), e1 = csub(b0, b2);
    float2 o0 = cadd(b1, b3), o1 = csub(b1, b3);
    y0 = cadd(e0, o0); y2 = csub(e0, o0);
    float2 r = make_float2((float)(-SGN) * o1.y, (float)SGN * o1.x);   // SGN*i * o1
    y1 = cadd(e1, r); y3 = csub(e1, r);
}

template<int SGN>
__device__ __forceinline__ void dft8(const float2* a, float2* X) {
    const float C = 0.70710678118654752f;
    float2 E0,E1,E2,E3,O0,O1,O2,O3;
    dft4<SGN>(a[0],a[2],a[4],a[6], E0,E1,E2,E3);
    dft4<SGN>(a[1],a[3],a[5],a[7], O0,O1,O2,O3);
    // w8^k = e^{SGN*2pi i k/8}: k=1 (C,SGN C); k=2 (0,SGN); k=3 (-C,SGN C)
    float2 T1 = make_float2(C*(O1.x - (float)SGN*O1.y), C*((float)SGN*O1.x + O1.y));
    float2 T2 = make_float2((float)(-SGN)*O2.y, (float)SGN*O2.x);
    float2 T3 = make_float2(-C*(O3.x + (float)SGN*O3.y), C*((float)SGN*O3.x - O3.y));
    X[0]=cadd(E0,O0); X[4]=csub(E0,O0);
    X[1]=cadd(E1,T1); X[5]=csub(E1,T1);
    X[2]=cadd(E2,T2); X[6]=csub(E2,T2);
    X[3]=cadd(E3,T3); X[7]=csub(E3,T3);
}

// 16-pt DFT via radix-4 (16 = 4x4), all-register
template<int SGN>
__device__ __forceinline__ void dft16(const float2* v, float2* X) {
    const float ct[10] = {1.f, 0.92387953251f, 0.70710678119f, 0.38268343236f, 0.f,
                          0.f, -0.70710678119f, 0.f, 0.f, -0.92387953251f};
    const float st[10] = {0.f, 0.38268343236f, 0.70710678119f, 0.92387953251f, 1.f,
                          0.f, 0.70710678119f, 0.f, 0.f, -0.38268343236f};
    float2 Z[16];
    #pragma unroll
    for (int h0 = 0; h0 < 4; ++h0) {
        float2 y0,y1,y2,y3;
        dft4<SGN>(v[h0], v[4+h0], v[8+h0], v[12+h0], y0,y1,y2,y3);
        float2 ys[4] = {y0,y1,y2,y3};
        #pragma unroll
        for (int k0 = 0; k0 < 4; ++k0) {
            int m = h0 * k0;
            float cc = ct[m], ss = (float)SGN * st[m];
            Z[k0*4 + h0] = make_float2(ys[k0].x*cc - ys[k0].y*ss,
                                       ys[k0].x*ss + ys[k0].y*cc);
        }
    }
    #pragma unroll
    for (int k0 = 0; k0 < 4; ++k0) {
        float2 y0,y1,y2,y3;
        dft4<SGN>(Z[k0*4+0], Z[k0*4+1], Z[k0*4+2], Z[k0*4+3], y0,y1,y2,y3);
        X[k0] = y0; X[k0+4] = y1; X[k0+8] = y2; X[k0+12] = y3;
    }
}

// ---------------- kernel preprocessing (tiny) ----------------

__global__ __launch_bounds__(256) void k0_tanh(const float* __restrict__ a,
                                               float* __restrict__ as, int n) {
    int i = blockIdx.x * 256 + threadIdx.x;
    if (i < n) as[i] = 0.9f * tanhf(a[i]);
}

__global__ __launch_bounds__(256) void k1a(const float* __restrict__ As,
                                           const float* __restrict__ Bk,
                                           float2* __restrict__ Aw,
                                           float2* __restrict__ Bw) {
    __shared__ float2 tw[64];
    for (int i = threadIdx.x; i < 64; i += 256) {
        float s, c; sincosf(-6.283185307179586f * i / 64.0f, &s, &c);
        tw[i] = make_float2(c, s);
    }
    __syncthreads();
    int i = blockIdx.x * 256 + threadIdx.x;   // 172032 total
    int c = i & 127;
    int om = (i >> 7) & 63;
    int rem = i >> 13;          // 0..20
    int kh = rem % 7, kt = rem / 7;
    int base = ((c * 3 + kt) * 7 + kh) * 7;
    float2 accA = make_float2(0.f, 0.f), accB = make_float2(0.f, 0.f);
    #pragma unroll
    for (int kw = 0; kw < 7; ++kw) {
        float2 t = tw[(om * (kw - 3)) & 63];
        float va = As[base + kw], vb = Bk[base + kw];
        accA.x = fmaf(va, t.x, accA.x); accA.y = fmaf(va, t.y, accA.y);
        accB.x = fmaf(vb, t.x, accB.x); accB.y = fmaf(vb, t.y, accB.y);
    }
    int o = ((kt * 7 + kh) * 64 + om) * 128 + c;
    Aw[o] = accA; Bw[o] = accB;
}

__global__ __launch_bounds__(256) void k1b(const float2* __restrict__ Aw,
                                           const float2* __restrict__ Bw,
                                           float2* __restrict__ Ahw,
                                           float2* __restrict__ Bhw) {
    __shared__ float2 tw[64];
    for (int i = threadIdx.x; i < 64; i += 256) {
        float s, c; sincosf(-6.283185307179586f * i / 64.0f, &s, &c);
        tw[i] = make_float2(c, s);
    }
    __syncthreads();
    int i = blockIdx.x * 256 + threadIdx.x;   // 1572864 total
    int c = i & 127, om = (i >> 7) & 63, eta = (i >> 13) & 63, kt = i >> 19;
    float2 accA = make_float2(0.f, 0.f), accB = make_float2(0.f, 0.f);
    #pragma unroll
    for (int kh = 0; kh < 7; ++kh) {
        float2 t = tw[(eta * (kh - 3)) & 63];
        int s = ((kt * 7 + kh) * 64 + om) * 128 + c;
        accA = cmac(accA, Aw[s], t);
        accB = cmac(accB, Bw[s], t);
    }
    int o = ((kt * 64 + eta) * 64 + om) * 128 + c;
    Ahw[o] = accA; Bhw[o] = accB;
}

// ---------------- pass 1: forward radix-8 FFT along W (real input) ----------------
__global__ __launch_bounds__(256) void p1(const float* __restrict__ x,
                                          float2* __restrict__ buf) {
    __shared__ float  rf[64][64];        // 16 KB real input tile
    __shared__ float2 zt[64][64];        // 32 KB stage-1 output
    __shared__ float2 tw64[64];
    int bid = blockIdx.x;
    int chalf = bid & 1, h = (bid >> 1) & 63, t = bid >> 7;
    for (int i = threadIdx.x; i < 64; i += 256) {
        float s, cq; sincosf(-6.283185307179586f * i / 64.0f, &s, &cq);
        tw64[i] = make_float2(cq, s);
    }
    const float* src = x + (size_t)(t * HH + h) * WW * CC + chalf * 64;
    for (int i = threadIdx.x; i < 4096; i += 256)
        rf[i >> 6][i & 63] = src[(size_t)(i >> 6) * CC + (i & 63)];
    __syncthreads();
    int c = threadIdx.x & 63, s4 = threadIdx.x >> 6;
    #pragma unroll
    for (int g = 0; g < 2; ++g) {
        int h0 = s4 * 2 + g;
        float2 a[8], Y[8];
        #pragma unroll
        for (int h1 = 0; h1 < 8; ++h1) a[h1] = make_float2(rf[h1 * 8 + h0][c], 0.f);
        dft8<-1>(a, Y);
        #pragma unroll
        for (int k0 = 0; k0 < 8; ++k0) zt[k0 * 8 + h0][c] = cmul(Y[k0], tw64[h0 * k0]);
    }
    __syncthreads();
    float2* dst = buf + (size_t)(t * HH + h) * WW * CC + chalf * 64 + c;
    #pragma unroll
    for (int g = 0; g < 2; ++g) {
        int k0 = s4 * 2 + g;
        float2 b[8], X[8];
        #pragma unroll
        for (int h0 = 0; h0 < 8; ++h0) b[h0] = zt[k0 * 8 + h0][c];
        dft8<-1>(b, X);
        #pragma unroll
        for (int k1 = 0; k1 < 8; ++k1) dst[(size_t)(k0 + 8 * k1) * CC] = X[k1];
    }
}

// ------- pass 2/4: radix-8 FFT along H, in place. SGN=-1 fwd, +1 inv -------
template<int SGN>
__global__ __launch_bounds__(256) void p2f(float2* __restrict__ buf) {
    __shared__ float2 tile[64][64];      // 32 KB
    __shared__ float2 tw64[64];
    int bid = blockIdx.x;
    int chalf = bid & 1, om = (bid >> 1) & 63, t = bid >> 7;
    for (int i = threadIdx.x; i < 64; i += 256) {
        float s, cq; sincosf((float)SGN * 6.283185307179586f * i / 64.0f, &s, &cq);
        tw64[i] = make_float2(cq, s);
    }
    float2* bptr = buf + (size_t)t * PLANE + om * CC + chalf * 64;
    for (int i = threadIdx.x; i < 4096; i += 256)
        tile[i >> 6][i & 63] = bptr[(size_t)(i >> 6) * WW * CC + (i & 63)];
    __syncthreads();
    int c = threadIdx.x & 63, s4 = threadIdx.x >> 6;
    // stage 1: DFT8 over h1 at fixed h0; rows {8j+h0} x col c owned exclusively
    #pragma unroll
    for (int g = 0; g < 2; ++g) {
        int h0 = s4 * 2 + g;
        float2 a[8], Y[8];
        #pragma unroll
        for (int h1 = 0; h1 < 8; ++h1) a[h1] = tile[h1 * 8 + h0][c];
        dft8<SGN>(a, Y);
        #pragma unroll
        for (int k0 = 0; k0 < 8; ++k0) tile[k0 * 8 + h0][c] = cmul(Y[k0], tw64[h0 * k0]);
    }
    __syncthreads();
    // stage 2: DFT8 over h0 at fixed k0
    #pragma unroll
    for (int g = 0; g < 2; ++g) {
        int k0 = s4 * 2 + g;
        float2 b[8], X[8];
        #pragma unroll
        for (int h0 = 0; h0 < 8; ++h0) b[h0] = tile[k0 * 8 + h0][c];
        dft8<SGN>(b, X);
        #pragma unroll
        for (int k1 = 0; k1 < 8; ++k1)
            bptr[(size_t)(k0 + 8 * k1) * WW * CC + c] = X[k1];
    }
}

// ------- pass 3: fwd 16-pt FFT along T + G=S(A_f)B_f multiply + inv FFT, in place -------
__global__ __launch_bounds__(256) void p3(float2* __restrict__ buf,
                                          const float2* __restrict__ Ahw,
                                          const float2* __restrict__ Bhw) {
    __shared__ float2 tw[16];
    if (threadIdx.x < 16) {
        float s, cq; sincosf(-6.283185307179586f * threadIdx.x / 16.0f, &s, &cq);
        tw[threadIdx.x] = make_float2(cq, s);
    }
    __syncthreads();
    int eta = blockIdx.x >> 5;
    int om = ((blockIdx.x & 31) << 1) + (threadIdx.x >> 7);
    int c = threadIdx.x & 127;
    size_t base = (size_t)(eta * WW + om) * CC + c;
    float2 v[16], X[16];
    #pragma unroll
    for (int t = 0; t < 16; ++t) v[t] = buf[(size_t)t * PLANE + base];
    dft16<-1>(v, X);
    // per-tau kernel response
    int kb = (eta * 64 + om) * 128 + c;
    float2 A0 = Ahw[kb], A1 = Ahw[kb + 524288], A2 = Ahw[kb + 1048576];
    float2 B0 = Bhw[kb], B1 = Bhw[kb + 524288], B2 = Bhw[kb + 1048576];
    #pragma unroll
    for (int ta = 0; ta < 16; ++ta) {
        float2 wv = tw[ta];
        float2 wc = make_float2(wv.x, -wv.y);
        // A_f = A1 + conj(w)*A0 + w*A2   (kt offsets -1,0,+1)
        float2 Af = A1; Af = cmac(Af, A0, wc); Af = cmac(Af, A2, wv);
        float2 Bf = B1; Bf = cmac(Bf, B0, wc); Bf = cmac(Bf, B2, wv);
        float2 S = make_float2(1.f, 0.f);
        #pragma unroll
        for (int k = 0; k < 7; ++k) {
            float2 t2 = cmul(Af, S);
            S = make_float2(1.f + t2.x, t2.y);
        }
        float2 G = cmul(S, Bf);
        X[ta] = cmul(X[ta], G);
    }
    dft16<1>(X, v);
    #pragma unroll
    for (int t = 0; t < 16; ++t) buf[(size_t)t * PLANE + base] = v[t];
}

// ---------------- pass 5: inverse radix-8 FFT along W, real out, scale ----------------
__global__ __launch_bounds__(256) void p5(const float2* __restrict__ buf,
                                          float* __restrict__ out) {
    __shared__ float2 tile[64][64];      // 32 KB
    __shared__ float2 tw64[64];
    int bid = blockIdx.x;
    int chalf = bid & 1, h = (bid >> 1) & 63, t = bid >> 7;
    for (int i = threadIdx.x; i < 64; i += 256) {
        float s, cq; sincosf(6.283185307179586f * i / 64.0f, &s, &cq);
        tw64[i] = make_float2(cq, s);
    }
    const float2* src = buf + (size_t)(t * HH + h) * WW * CC + chalf * 64;
    for (int i = threadIdx.x; i < 4096; i += 256)
        tile[i >> 6][i & 63] = src[(size_t)(i >> 6) * CC + (i & 63)];
    __syncthreads();
    int c = threadIdx.x & 63, s4 = threadIdx.x >> 6;
    #pragma unroll
    for (int g = 0; g < 2; ++g) {
        int h0 = s4 * 2 + g;
        float2 a[8], Y[8];
        #pragma unroll
        for (int h1 = 0; h1 < 8; ++h1) a[h1] = tile[h1 * 8 + h0][c];
        dft8<1>(a, Y);
        #pragma unroll
        for (int k0 = 0; k0 < 8; ++k0) tile[k0 * 8 + h0][c] = cmul(Y[k0], tw64[h0 * k0]);
    }
    __syncthreads();
    float* dst = out + (size_t)(t * HH + h) * WW * CC + chalf * 64 + c;
    #pragma unroll
    for (int g = 0; g < 2; ++g) {
        int k0 = s4 * 2 + g;
        float2 b[8], X[8];
        #pragma unroll
        for (int h0 = 0; h0 < 8; ++h0) b[h0] = tile[k0 * 8 + h0][c];
        dft8<1>(b, X);
        #pragma unroll
        for (int k1 = 0; k1 < 8; ++k1)
            dst[(size_t)(k0 + 8 * k1) * CC] = X[k1].x * (1.0f / 65536.0f);
    }
}

extern "C" void kernel_launch(void* const* d_in, const int* in_sizes, int n_in,
                              void* d_out, int out_size, void* d_ws, size_t ws_size,
                              hipStream_t stream) {
    const float* x  = (const float*)d_in[0];
    const float* Ak = (const float*)d_in[1];
    const float* Bk = (const float*)d_in[2];
    float* out = (float*)d_out;

    float2* buf = (float2*)d_ws;
    float2* Ahw = buf + TOTALC;
    float2* Bhw = Ahw + 3 * 64 * 64 * 128;
    float2* Aw  = Bhw + 3 * 64 * 64 * 128;
    float2* Bw  = Aw + 3 * 7 * 64 * 128;
    float*  As  = (float*)(Bw + 3 * 7 * 64 * 128);

    hipLaunchKernelGGL(k0_tanh, dim3(74),   dim3(256), 0, stream, Ak, As, 18816);
    hipLaunchKernelGGL(k1a,     dim3(672),  dim3(256), 0, stream, As, Bk, Aw, Bw);
    hipLaunchKernelGGL(k1b,     dim3(6144), dim3(256), 0, stream, Aw, Bw, Ahw, Bhw);
    hipLaunchKernelGGL(p1,      dim3(2048), dim3(256), 0, stream, x, buf);
    hipLaunchKernelGGL(p2f<-1>, dim3(2048), dim3(256), 0, stream, buf);
    hipLaunchKernelGGL(p3,      dim3(2048), dim3(256), 0, stream, buf, Ahw, Bhw);
    hipLaunchKernelGGL(p2f<1>,  dim3(2048), dim3(256), 0, stream, buf);
    hipLaunchKernelGGL(p5,      dim3(2048), dim3(256), 0, stream, buf, out);
}

// Round 3
// 97.390 us; speedup vs baseline: 4.0653x; 1.5528x over previous
//
#include <hip/hip_runtime.h>
#include <math.h>

#define TT 16
#define HH 64
#define WW 64
#define CC 128

// XOR row swizzle: logical row r -> physical row, keeps all stride-8 / block-8
// LDS accesses at <=2-way bank aliasing with zero padding (tile is exactly 64KB).
#define LROW(r) (((r) & 0x38) | ((((r) >> 3) ^ (r)) & 7))

__device__ __forceinline__ float2 cadd(float2 a, float2 b){ return make_float2(a.x+b.x, a.y+b.y); }
__device__ __forceinline__ float2 csub(float2 a, float2 b){ return make_float2(a.x-b.x, a.y-b.y); }
__device__ __forceinline__ float2 cmul(float2 a, float2 b) {
    return make_float2(a.x*b.x - a.y*b.y, a.x*b.y + a.y*b.x);
}
__device__ __forceinline__ float2 cmac(float2 acc, float2 a, float2 b) {
    acc.x = fmaf(a.x, b.x, fmaf(-a.y, b.y, acc.x));
    acc.y = fmaf(a.x, b.y, fmaf(a.y, b.x, acc.y));
    return acc;
}

// ---------------- radix butterflies ----------------
template<int SGN>
__device__ __forceinline__ void dft4(float2 b0, float2 b1, float2 b2, float2 b3,
                                     float2& y0, float2& y1, float2& y2, float2& y3) {
    float2 e0 = cadd(b0, b2), e1 = csub(b0, b2);
    float2 o0 = cadd(b1, b3), o1 = csub(b1, b3);
    y0 = cadd(e0, o0); y2 = csub(e0, o0);
    float2 r = make_float2((float)(-SGN) * o1.y, (float)SGN * o1.x);
    y1 = cadd(e1, r); y3 = csub(e1, r);
}

template<int SGN>
__device__ __forceinline__ void dft8(const float2* a, float2* X) {
    const float C = 0.70710678118654752f;
    float2 E0,E1,E2,E3,O0,O1,O2,O3;
    dft4<SGN>(a[0],a[2],a[4],a[6], E0,E1,E2,E3);
    dft4<SGN>(a[1],a[3],a[5],a[7], O0,O1,O2,O3);
    float2 T1 = make_float2(C*(O1.x - (float)SGN*O1.y), C*((float)SGN*O1.x + O1.y));
    float2 T2 = make_float2((float)(-SGN)*O2.y, (float)SGN*O2.x);
    float2 T3 = make_float2(-C*(O3.x + (float)SGN*O3.y), C*((float)SGN*O3.x - O3.y));
    X[0]=cadd(E0,O0); X[4]=csub(E0,O0);
    X[1]=cadd(E1,T1); X[5]=csub(E1,T1);
    X[2]=cadd(E2,T2); X[6]=csub(E2,T2);
    X[3]=cadd(E3,T3); X[7]=csub(E3,T3);
}

template<int SGN>
__device__ __forceinline__ void dft16(const float2* v, float2* X) {
    const float ct[10] = {1.f, 0.92387953251f, 0.70710678119f, 0.38268343236f, 0.f,
                          0.f, -0.70710678119f, 0.f, 0.f, -0.92387953251f};
    const float st[10] = {0.f, 0.38268343236f, 0.70710678119f, 0.92387953251f, 1.f,
                          0.f, 0.70710678119f, 0.f, 0.f, -0.38268343236f};
    float2 Z[16];
    #pragma unroll
    for (int h0 = 0; h0 < 4; ++h0) {
        float2 y0,y1,y2,y3;
        dft4<SGN>(v[h0], v[4+h0], v[8+h0], v[12+h0], y0,y1,y2,y3);
        float2 ys[4] = {y0,y1,y2,y3};
        #pragma unroll
        for (int k0 = 0; k0 < 4; ++k0) {
            int m = h0 * k0;
            float cc = ct[m], ss = (float)SGN * st[m];
            Z[k0*4 + h0] = make_float2(ys[k0].x*cc - ys[k0].y*ss,
                                       ys[k0].x*ss + ys[k0].y*cc);
        }
    }
    #pragma unroll
    for (int k0 = 0; k0 < 4; ++k0) {
        float2 y0,y1,y2,y3;
        dft4<SGN>(Z[k0*4+0], Z[k0*4+1], Z[k0*4+2], Z[k0*4+3], y0,y1,y2,y3);
        X[k0] = y0; X[k0+4] = y1; X[k0+8] = y2; X[k0+12] = y3;
    }
}

// ---------------- kernel preprocessing (tiny) ----------------

__global__ __launch_bounds__(256) void k0_tanh(const float* __restrict__ a,
                                               float* __restrict__ as, int n) {
    int i = blockIdx.x * 256 + threadIdx.x;
    if (i < n) as[i] = 0.9f * tanhf(a[i]);
}

__global__ __launch_bounds__(256) void k1a(const float* __restrict__ As,
                                           const float* __restrict__ Bk,
                                           float2* __restrict__ Aw,
                                           float2* __restrict__ Bw) {
    __shared__ float2 tw[64];
    for (int i = threadIdx.x; i < 64; i += 256) {
        float s, c; sincosf(-6.283185307179586f * i / 64.0f, &s, &c);
        tw[i] = make_float2(c, s);
    }
    __syncthreads();
    int i = blockIdx.x * 256 + threadIdx.x;
    int c = i & 127;
    int om = (i >> 7) & 63;
    if (om > 32) return;                       // Hermitian: only omega<=32 needed
    int rem = i >> 13;
    int kh = rem % 7, kt = rem / 7;
    int base = ((c * 3 + kt) * 7 + kh) * 7;
    float2 accA = make_float2(0.f, 0.f), accB = make_float2(0.f, 0.f);
    #pragma unroll
    for (int kw = 0; kw < 7; ++kw) {
        float2 t = tw[(om * (kw - 3)) & 63];
        float va = As[base + kw], vb = Bk[base + kw];
        accA.x = fmaf(va, t.x, accA.x); accA.y = fmaf(va, t.y, accA.y);
        accB.x = fmaf(vb, t.x, accB.x); accB.y = fmaf(vb, t.y, accB.y);
    }
    int o = ((kt * 7 + kh) * 64 + om) * 128 + c;
    Aw[o] = accA; Bw[o] = accB;
}

__global__ __launch_bounds__(256) void k1b(const float2* __restrict__ Aw,
                                           const float2* __restrict__ Bw,
                                           float2* __restrict__ Ahw,
                                           float2* __restrict__ Bhw) {
    __shared__ float2 tw[64];
    for (int i = threadIdx.x; i < 64; i += 256) {
        float s, c; sincosf(-6.283185307179586f * i / 64.0f, &s, &c);
        tw[i] = make_float2(c, s);
    }
    __syncthreads();
    int i = blockIdx.x * 256 + threadIdx.x;
    int c = i & 127, om = (i >> 7) & 63, eta = (i >> 13) & 63, kt = i >> 19;
    if (om > 32) return;                       // Hermitian
    float2 accA = make_float2(0.f, 0.f), accB = make_float2(0.f, 0.f);
    #pragma unroll
    for (int kh = 0; kh < 7; ++kh) {
        float2 t = tw[(eta * (kh - 3)) & 63];
        int s = ((kt * 7 + kh) * 64 + om) * 128 + c;
        accA = cmac(accA, Aw[s], t);
        accB = cmac(accB, Bw[s], t);
    }
    // store at digit-swapped eta position: pmid's LDS row r holds bin (r>>3)+8*(r&7),
    // so bin eta belongs at position ((eta&7)<<3)|(eta>>3).
    int ep = ((eta & 7) << 3) | (eta >> 3);
    int o = ((kt * 64 + ep) * 64 + om) * 128 + c;
    Ahw[o] = accA; Bhw[o] = accB;
}

// ------- pass 1: forward radix-8 FFT along W (real input), write omega<=32 -------
__global__ __launch_bounds__(256) void p1(const float* __restrict__ x,
                                          float2* __restrict__ buf) {
    __shared__ float rf[64][64];          // 16 KB
    __shared__ float zre[64][64];         // 16 KB
    __shared__ float zim[64][64];         // 16 KB
    __shared__ float2 tw64[64];
    int bid = blockIdx.x;
    int chalf = bid & 1, h = (bid >> 1) & 63, t = bid >> 7;
    for (int i = threadIdx.x; i < 64; i += 256) {
        float s, cq; sincosf(-6.283185307179586f * i / 64.0f, &s, &cq);
        tw64[i] = make_float2(cq, s);
    }
    const float* src = x + (size_t)(t * HH + h) * WW * CC + chalf * 64;
    for (int i = threadIdx.x; i < 4096; i += 256)
        rf[i >> 6][i & 63] = src[(size_t)(i >> 6) * CC + (i & 63)];
    __syncthreads();
    int c = threadIdx.x & 63, s4 = threadIdx.x >> 6;
    #pragma unroll
    for (int g = 0; g < 2; ++g) {
        int h0 = s4 * 2 + g;
        float2 a[8], Y[8];
        #pragma unroll
        for (int h1 = 0; h1 < 8; ++h1) a[h1] = make_float2(rf[h1 * 8 + h0][c], 0.f);
        dft8<-1>(a, Y);
        #pragma unroll
        for (int k0 = 0; k0 < 8; ++k0) {
            float2 z = cmul(Y[k0], tw64[h0 * k0]);
            zre[k0 * 8 + h0][c] = z.x; zim[k0 * 8 + h0][c] = z.y;
        }
    }
    __syncthreads();
    float2* dst = buf + (size_t)(t * HH + h) * WW * CC + chalf * 64 + c;
    #pragma unroll
    for (int g = 0; g < 2; ++g) {
        int k0 = s4 * 2 + g;
        float2 b[8], X[8];
        #pragma unroll
        for (int h0 = 0; h0 < 8; ++h0)
            b[h0] = make_float2(zre[k0 * 8 + h0][c], zim[k0 * 8 + h0][c]);
        dft8<-1>(b, X);
        #pragma unroll
        for (int k1 = 0; k1 < 8; ++k1) {
            int om = k0 + 8 * k1;
            if (om <= 32) dst[(size_t)om * CC] = X[k1];
        }
    }
}

// ------- fused middle pass: H-FFT + T-FFT + G multiply + inv-T + inv-H, in place -------
// One block per (omega in [0..32], 8-channel chunk). 64KB LDS SoA tile [t][row][c].
__global__ __launch_bounds__(256) void pmid(float2* __restrict__ buf,
                                            const float2* __restrict__ Ahw,
                                            const float2* __restrict__ Bhw) {
    __shared__ float tre[16][64][8];      // 32 KB
    __shared__ float tim[16][64][8];      // 32 KB
    // XCD-chunked swizzle: 528 = 8*66, consecutive logical blocks share an XCD L2
    int l = (blockIdx.x & 7) * 66 + (blockIdx.x >> 3);
    int om = l >> 4, cc = l & 15;
    int c0 = cc * 8;
    int tid = threadIdx.x;
    int d = tid & 7;                       // radix digit for H stages
    // per-thread twiddles w64^{-d*k} = (twc[k], tws[k])
    float twc[8], tws[8];
    {
        float s1, c1; sincosf(-6.283185307179586f * d / 64.0f, &s1, &c1);
        twc[0] = 1.f; tws[0] = 0.f;
        #pragma unroll
        for (int k = 1; k < 8; ++k) {
            twc[k] = twc[k-1]*c1 - tws[k-1]*s1;
            tws[k] = twc[k-1]*s1 + tws[k-1]*c1;
        }
    }
    // load tile
    for (int i = tid; i < 8192; i += 256) {
        int t = i >> 9, h = (i >> 3) & 63, c = i & 7;
        float2 v = buf[(size_t)((t*64 + h)*64 + om)*128 + c0 + c];
        int pr = LROW(h);
        tre[t][pr][c] = v.x; tim[t][pr][c] = v.y;
    }
    __syncthreads();
    int cl = (tid >> 3) & 7, ts = tid >> 6;
    // H forward stage 1: DFT8 over h1 at fixed h0=d, twiddle w^{-d*k0}
    for (int q = 0; q < 4; ++q) {
        int t = ts*4 + q;
        float2 a[8], Y[8];
        #pragma unroll
        for (int h1 = 0; h1 < 8; ++h1) {
            int pr = LROW(h1*8 + d);
            a[h1] = make_float2(tre[t][pr][cl], tim[t][pr][cl]);
        }
        dft8<-1>(a, Y);
        #pragma unroll
        for (int k0 = 0; k0 < 8; ++k0) {
            int pr = LROW(k0*8 + d);
            tre[t][pr][cl] = Y[k0].x*twc[k0] - Y[k0].y*tws[k0];
            tim[t][pr][cl] = Y[k0].x*tws[k0] + Y[k0].y*twc[k0];
        }
    }
    __syncthreads();
    // H forward stage 2: DFT8 over h0 at fixed k0=d; row k0*8+k1 := bin k0+8*k1
    for (int q = 0; q < 4; ++q) {
        int t = ts*4 + q;
        float2 a[8], Y[8];
        #pragma unroll
        for (int h0 = 0; h0 < 8; ++h0) {
            int pr = LROW(d*8 + h0);
            a[h0] = make_float2(tre[t][pr][cl], tim[t][pr][cl]);
        }
        dft8<-1>(a, Y);
        #pragma unroll
        for (int k1 = 0; k1 < 8; ++k1) {
            int pr = LROW(d*8 + k1);
            tre[t][pr][cl] = Y[k1].x; tim[t][pr][cl] = Y[k1].y;
        }
    }
    __syncthreads();
    // T phase: fwd dft16, G = S(A_f)*B_f multiply, inv dft16. Row r holds eta-swapped
    // data; Ahw/Bhw were pre-permuted in k1b so table index == r.
    {
        const float CT16[16] = {1.f, 0.9238795325f, 0.7071067812f, 0.3826834324f, 0.f,
                                -0.3826834324f, -0.7071067812f, -0.9238795325f, -1.f,
                                -0.9238795325f, -0.7071067812f, -0.3826834324f, 0.f,
                                0.3826834324f, 0.7071067812f, 0.9238795325f};
        const float ST16[16] = {0.f, 0.3826834324f, 0.7071067812f, 0.9238795325f, 1.f,
                                0.9238795325f, 0.7071067812f, 0.3826834324f, 0.f,
                                -0.3826834324f, -0.7071067812f, -0.9238795325f, -1.f,
                                -0.9238795325f, -0.7071067812f, -0.3826834324f};
        int cg = tid & 7, r0 = tid >> 3;           // r0 in [0,32)
        for (int j = 0; j < 2; ++j) {
            int r = r0 + 32*j;
            int pr = LROW(r);
            float2 v[16], X[16];
            #pragma unroll
            for (int t = 0; t < 16; ++t) v[t] = make_float2(tre[t][pr][cg], tim[t][pr][cg]);
            dft16<-1>(v, X);
            int kb = (r*64 + om)*128 + c0 + cg;
            float2 A0 = Ahw[kb], A1 = Ahw[kb + 524288], A2 = Ahw[kb + 1048576];
            float2 B0 = Bhw[kb], B1 = Bhw[kb + 524288], B2 = Bhw[kb + 1048576];
            #pragma unroll
            for (int ta = 0; ta < 16; ++ta) {
                float2 wv = make_float2(CT16[ta], -ST16[ta]);
                float2 wc = make_float2(CT16[ta],  ST16[ta]);
                float2 Af = A1; Af = cmac(Af, A0, wc); Af = cmac(Af, A2, wv);
                float2 Bf = B1; Bf = cmac(Bf, B0, wc); Bf = cmac(Bf, B2, wv);
                float2 S = make_float2(1.f, 0.f);
                #pragma unroll
                for (int k = 0; k < 7; ++k) {
                    float2 t2 = cmul(Af, S);
                    S = make_float2(1.f + t2.x, t2.y);
                }
                float2 G = cmul(S, Bf);
                X[ta] = cmul(X[ta], G);
            }
            dft16<1>(X, v);
            #pragma unroll
            for (int t = 0; t < 16; ++t) { tre[t][pr][cg] = v[t].x; tim[t][pr][cg] = v[t].y; }
        }
    }
    __syncthreads();
    // inverse H stage 1: DFT8<+1> over eta1 at fixed eta0=d, twiddle w^{+d*h0}
    for (int q = 0; q < 4; ++q) {
        int t = ts*4 + q;
        float2 a[8], Y[8];
        #pragma unroll
        for (int e1 = 0; e1 < 8; ++e1) {
            int pr = LROW(d*8 + e1);
            a[e1] = make_float2(tre[t][pr][cl], tim[t][pr][cl]);
        }
        dft8<1>(a, Y);
        #pragma unroll
        for (int h0 = 0; h0 < 8; ++h0) {
            int pr = LROW(d*8 + h0);
            tre[t][pr][cl] =  Y[h0].x*twc[h0] + Y[h0].y*tws[h0];
            tim[t][pr][cl] = -Y[h0].x*tws[h0] + Y[h0].y*twc[h0];
        }
    }
    __syncthreads();
    // inverse H stage 2: DFT8<+1> over eta0 at fixed h0=d; out row d+8*h1 (natural h)
    for (int q = 0; q < 4; ++q) {
        int t = ts*4 + q;
        float2 a[8], Y[8];
        #pragma unroll
        for (int e0 = 0; e0 < 8; ++e0) {
            int pr = LROW(e0*8 + d);
            a[e0] = make_float2(tre[t][pr][cl], tim[t][pr][cl]);
        }
        dft8<1>(a, Y);
        #pragma unroll
        for (int h1 = 0; h1 < 8; ++h1) {
            int pr = LROW(d + 8*h1);
            tre[t][pr][cl] = Y[h1].x; tim[t][pr][cl] = Y[h1].y;
        }
    }
    __syncthreads();
    // write back
    for (int i = tid; i < 8192; i += 256) {
        int t = i >> 9, h = (i >> 3) & 63, c = i & 7;
        int pr = LROW(h);
        buf[(size_t)((t*64 + h)*64 + om)*128 + c0 + c] = make_float2(tre[t][pr][c], tim[t][pr][c]);
    }
}

// ------- pass 5: Hermitian-expand + inverse radix-8 FFT along W, real out, scale -------
__global__ __launch_bounds__(256) void p5(const float2* __restrict__ buf,
                                          float* __restrict__ out) {
    __shared__ float tre[64][64];         // 16 KB
    __shared__ float tim[64][64];         // 16 KB
    __shared__ float2 tw64[64];
    int bid = blockIdx.x;
    int chalf = bid & 1, h = (bid >> 1) & 63, t = bid >> 7;
    for (int i = threadIdx.x; i < 64; i += 256) {
        float s, cq; sincosf(6.283185307179586f * i / 64.0f, &s, &cq);
        tw64[i] = make_float2(cq, s);
    }
    const float2* src = buf + (size_t)(t * HH + h) * WW * CC + chalf * 64;
    for (int i = threadIdx.x; i < 33 * 64; i += 256) {
        int om = i >> 6, c = i & 63;
        float2 v = src[(size_t)om * CC + c];
        tre[om][c] = v.x; tim[om][c] = v.y;
        if (om >= 1 && om <= 31) {        // Hermitian mirror
            tre[64 - om][c] = v.x; tim[64 - om][c] = -v.y;
        }
    }
    __syncthreads();
    int c = threadIdx.x & 63, s4 = threadIdx.x >> 6;
    #pragma unroll
    for (int g = 0; g < 2; ++g) {
        int h0 = s4 * 2 + g;
        float2 a[8], Y[8];
        #pragma unroll
        for (int h1 = 0; h1 < 8; ++h1)
            a[h1] = make_float2(tre[h1 * 8 + h0][c], tim[h1 * 8 + h0][c]);
        dft8<1>(a, Y);
        #pragma unroll
        for (int k0 = 0; k0 < 8; ++k0) {
            float2 z = cmul(Y[k0], tw64[h0 * k0]);
            tre[k0 * 8 + h0][c] = z.x; tim[k0 * 8 + h0][c] = z.y;
        }
    }
    __syncthreads();
    float* dst = out + (size_t)(t * HH + h) * WW * CC + chalf * 64 + c;
    #pragma unroll
    for (int g = 0; g < 2; ++g) {
        int k0 = s4 * 2 + g;
        float2 b[8], X[8];
        #pragma unroll
        for (int h0 = 0; h0 < 8; ++h0)
            b[h0] = make_float2(tre[k0 * 8 + h0][c], tim[k0 * 8 + h0][c]);
        dft8<1>(b, X);
        #pragma unroll
        for (int k1 = 0; k1 < 8; ++k1)
            dst[(size_t)(k0 + 8 * k1) * CC] = X[k1].x * (1.0f / 65536.0f);
    }
}

extern "C" void kernel_launch(void* const* d_in, const int* in_sizes, int n_in,
                              void* d_out, int out_size, void* d_ws, size_t ws_size,
                              hipStream_t stream) {
    const float* x  = (const float*)d_in[0];
    const float* Ak = (const float*)d_in[1];
    const float* Bk = (const float*)d_in[2];
    float* out = (float*)d_out;

    float2* buf = (float2*)d_ws;                       // 16*64*64*128 float2
    float2* Ahw = buf + (size_t)TT * HH * WW * CC;
    float2* Bhw = Ahw + 3 * 64 * 64 * 128;
    float2* Aw  = Bhw + 3 * 64 * 64 * 128;
    float2* Bw  = Aw + 3 * 7 * 64 * 128;
    float*  As  = (float*)(Bw + 3 * 7 * 64 * 128);

    hipLaunchKernelGGL(k0_tanh, dim3(74),   dim3(256), 0, stream, Ak, As, 18816);
    hipLaunchKernelGGL(k1a,     dim3(672),  dim3(256), 0, stream, As, Bk, Aw, Bw);
    hipLaunchKernelGGL(k1b,     dim3(6144), dim3(256), 0, stream, Aw, Bw, Ahw, Bhw);
    hipLaunchKernelGGL(p1,      dim3(2048), dim3(256), 0, stream, x, buf);
    hipLaunchKernelGGL(pmid,    dim3(528),  dim3(256), 0, stream, buf, Ahw, Bhw);
    hipLaunchKernelGGL(p5,      dim3(2048), dim3(256), 0, stream, buf, out);
}

// Round 4
// 76.710 us; speedup vs baseline: 5.1612x; 1.2696x over previous
//
#include <hip/hip_runtime.h>
#include <math.h>

#define TT 16
#define HH 64
#define WW 64
#define CC 128

// XOR row swizzle: logical row r -> physical row, keeps all stride-8 / block-8
// LDS accesses at <=2-way bank aliasing with zero padding.
#define LROW(r) (((r) & 0x38) | ((((r) >> 3) ^ (r)) & 7))

__device__ __forceinline__ float2 cadd(float2 a, float2 b){ return make_float2(a.x+b.x, a.y+b.y); }
__device__ __forceinline__ float2 csub(float2 a, float2 b){ return make_float2(a.x-b.x, a.y-b.y); }
__device__ __forceinline__ float2 cmul(float2 a, float2 b) {
    return make_float2(a.x*b.x - a.y*b.y, a.x*b.y + a.y*b.x);
}
__device__ __forceinline__ float2 cmac(float2 acc, float2 a, float2 b) {
    acc.x = fmaf(a.x, b.x, fmaf(-a.y, b.y, acc.x));
    acc.y = fmaf(a.x, b.y, fmaf(a.y, b.x, acc.y));
    return acc;
}
__device__ __forceinline__ float2 csq(float2 a) {
    return make_float2(a.x*a.x - a.y*a.y, 2.f*a.x*a.y);
}

// ---------------- radix butterflies ----------------
template<int SGN>
__device__ __forceinline__ void dft4(float2 b0, float2 b1, float2 b2, float2 b3,
                                     float2& y0, float2& y1, float2& y2, float2& y3) {
    float2 e0 = cadd(b0, b2), e1 = csub(b0, b2);
    float2 o0 = cadd(b1, b3), o1 = csub(b1, b3);
    y0 = cadd(e0, o0); y2 = csub(e0, o0);
    float2 r = make_float2((float)(-SGN) * o1.y, (float)SGN * o1.x);
    y1 = cadd(e1, r); y3 = csub(e1, r);
}

template<int SGN>
__device__ __forceinline__ void dft8(const float2* a, float2* X) {
    const float C = 0.70710678118654752f;
    float2 E0,E1,E2,E3,O0,O1,O2,O3;
    dft4<SGN>(a[0],a[2],a[4],a[6], E0,E1,E2,E3);
    dft4<SGN>(a[1],a[3],a[5],a[7], O0,O1,O2,O3);
    float2 T1 = make_float2(C*(O1.x - (float)SGN*O1.y), C*((float)SGN*O1.x + O1.y));
    float2 T2 = make_float2((float)(-SGN)*O2.y, (float)SGN*O2.x);
    float2 T3 = make_float2(-C*(O3.x + (float)SGN*O3.y), C*((float)SGN*O3.x - O3.y));
    X[0]=cadd(E0,O0); X[4]=csub(E0,O0);
    X[1]=cadd(E1,T1); X[5]=csub(E1,T1);
    X[2]=cadd(E2,T2); X[6]=csub(E2,T2);
    X[3]=cadd(E3,T3); X[7]=csub(E3,T3);
}

template<int SGN>
__device__ __forceinline__ void dft16(const float2* v, float2* X) {
    const float ct[10] = {1.f, 0.92387953251f, 0.70710678119f, 0.38268343236f, 0.f,
                          0.f, -0.70710678119f, 0.f, 0.f, -0.92387953251f};
    const float st[10] = {0.f, 0.38268343236f, 0.70710678119f, 0.92387953251f, 1.f,
                          0.f, 0.70710678119f, 0.f, 0.f, -0.38268343236f};
    float2 Z[16];
    #pragma unroll
    for (int h0 = 0; h0 < 4; ++h0) {
        float2 y0,y1,y2,y3;
        dft4<SGN>(v[h0], v[4+h0], v[8+h0], v[12+h0], y0,y1,y2,y3);
        float2 ys[4] = {y0,y1,y2,y3};
        #pragma unroll
        for (int k0 = 0; k0 < 4; ++k0) {
            int m = h0 * k0;
            float cc = ct[m], ss = (float)SGN * st[m];
            Z[k0*4 + h0] = make_float2(ys[k0].x*cc - ys[k0].y*ss,
                                       ys[k0].x*ss + ys[k0].y*cc);
        }
    }
    #pragma unroll
    for (int k0 = 0; k0 < 4; ++k0) {
        float2 y0,y1,y2,y3;
        dft4<SGN>(Z[k0*4+0], Z[k0*4+1], Z[k0*4+2], Z[k0*4+3], y0,y1,y2,y3);
        X[k0] = y0; X[k0+4] = y1; X[k0+8] = y2; X[k0+12] = y3;
    }
}

// ---------------- fused kernel prep: tanh + kw-DFT + kh-DFT ----------------
// grid: kt(3) x om(33) x chalf(2) = 198 blocks. Output layout [kt][om(33)][ep][c].
__global__ __launch_bounds__(256) void k_prep(const float* __restrict__ Ak,
                                              const float* __restrict__ Bk,
                                              float2* __restrict__ Ahw,
                                              float2* __restrict__ Bhw) {
    __shared__ float Asl[7][7][64];      // 12.25 KB
    __shared__ float Bsl[7][7][64];      // 12.25 KB
    __shared__ float2 Awl[7][64];        // 3.5 KB
    __shared__ float2 Bwl[7][64];        // 3.5 KB
    __shared__ float2 tw64[64];          // 0.5 KB
    int bid = blockIdx.x;
    int kt = bid / 66;
    int rem = bid % 66;
    int om = rem >> 1, chalf = rem & 1;
    int c0 = chalf * 64;
    int tid = threadIdx.x;
    for (int i = tid; i < 64; i += 256) {
        float s, cq; sincosf(-6.283185307179586f * i / 64.0f, &s, &cq);
        tw64[i] = make_float2(cq, s);
    }
    // load + tanh
    for (int i = tid; i < 49 * 64; i += 256) {
        int p = i >> 6, cl = i & 63;
        int kh = p / 7, kw = p % 7;
        int idx = (((c0 + cl) * 3 + kt) * 7 + kh) * 7 + kw;
        Asl[kh][kw][cl] = 0.9f * tanhf(Ak[idx]);
        Bsl[kh][kw][cl] = Bk[idx];
    }
    __syncthreads();
    // stage 1: DFT over kw
    for (int i = tid; i < 7 * 64; i += 256) {
        int kh = i >> 6, cl = i & 63;
        float2 aA = make_float2(0.f,0.f), aB = make_float2(0.f,0.f);
        #pragma unroll
        for (int kw = 0; kw < 7; ++kw) {
            float2 t = tw64[(om * (kw - 3)) & 63];
            float va = Asl[kh][kw][cl], vb = Bsl[kh][kw][cl];
            aA.x = fmaf(va, t.x, aA.x); aA.y = fmaf(va, t.y, aA.y);
            aB.x = fmaf(vb, t.x, aB.x); aB.y = fmaf(vb, t.y, aB.y);
        }
        Awl[kh][cl] = aA; Bwl[kh][cl] = aB;
    }
    __syncthreads();
    // stage 2: DFT over kh, write at digit-swapped eta position
    for (int i = tid; i < 64 * 64; i += 256) {
        int eta = i >> 6, cl = i & 63;
        float2 aA = make_float2(0.f,0.f), aB = make_float2(0.f,0.f);
        #pragma unroll
        for (int kh = 0; kh < 7; ++kh) {
            float2 t = tw64[(eta * (kh - 3)) & 63];
            aA = cmac(aA, Awl[kh][cl], t);
            aB = cmac(aB, Bwl[kh][cl], t);
        }
        int ep = ((eta & 7) << 3) | (eta >> 3);
        int o = ((kt * 33 + om) * 64 + ep) * 128 + c0 + cl;
        Ahw[o] = aA; Bhw[o] = aB;
    }
}

// ------- pass 1: forward radix-8 FFT along W (real input), write omega<=32 -------
__global__ __launch_bounds__(256) void p1(const float* __restrict__ x,
                                          float2* __restrict__ buf) {
    __shared__ float rf[64][64];          // 16 KB: input real, then stage-1 re
    __shared__ float zim[64][64];         // 16 KB: stage-1 im
    __shared__ float2 tw64[64];
    int bid = blockIdx.x;
    int chalf = bid & 1, h = (bid >> 1) & 63, t = bid >> 7;
    for (int i = threadIdx.x; i < 64; i += 256) {
        float s, cq; sincosf(-6.283185307179586f * i / 64.0f, &s, &cq);
        tw64[i] = make_float2(cq, s);
    }
    const float* src = x + (size_t)(t * HH + h) * WW * CC + chalf * 64;
    for (int i = threadIdx.x; i < 4096; i += 256)
        rf[i >> 6][i & 63] = src[(size_t)(i >> 6) * CC + (i & 63)];
    __syncthreads();
    int c = threadIdx.x & 63, s4 = threadIdx.x >> 6;
    #pragma unroll
    for (int g = 0; g < 2; ++g) {
        int h0 = s4 * 2 + g;
        float2 a[8], Y[8];
        #pragma unroll
        for (int h1 = 0; h1 < 8; ++h1) a[h1] = make_float2(rf[h1 * 8 + h0][c], 0.f);
        dft8<-1>(a, Y);
        #pragma unroll
        for (int k0 = 0; k0 < 8; ++k0) {
            float2 z = cmul(Y[k0], tw64[h0 * k0]);
            rf[k0 * 8 + h0][c] = z.x; zim[k0 * 8 + h0][c] = z.y;
        }
    }
    __syncthreads();
    float2* dst = buf + (size_t)(t * HH + h) * WW * CC + chalf * 64 + c;
    #pragma unroll
    for (int g = 0; g < 2; ++g) {
        int k0 = s4 * 2 + g;
        float2 b[8], X[8];
        #pragma unroll
        for (int h0 = 0; h0 < 8; ++h0)
            b[h0] = make_float2(rf[k0 * 8 + h0][c], zim[k0 * 8 + h0][c]);
        dft8<-1>(b, X);
        #pragma unroll
        for (int k1 = 0; k1 < 8; ++k1) {
            int om = k0 + 8 * k1;
            if (om <= 32) dst[(size_t)om * CC] = X[k1];
        }
    }
}

// ------- fused middle pass: H-FFT + T-FFT + G multiply + inv-T + inv-H, in place -------
// 512 threads, one block per (omega in [0..32], 8-channel chunk). 64KB LDS SoA tile.
__global__ __launch_bounds__(512, 4) void pmid(float2* __restrict__ buf,
                                               const float2* __restrict__ Ahw,
                                               const float2* __restrict__ Bhw) {
    __shared__ float tre[16][64][8];      // 32 KB
    __shared__ float tim[16][64][8];      // 32 KB
    // XCD-chunked swizzle: 528 = 8*66
    int l = (blockIdx.x & 7) * 66 + (blockIdx.x >> 3);
    int om = l >> 4, cc = l & 15;
    int c0 = cc * 8;
    int tid = threadIdx.x;
    int d = tid & 7;
    float twc[8], tws[8];
    {
        float s1, c1; sincosf(-6.283185307179586f * d / 64.0f, &s1, &c1);
        twc[0] = 1.f; tws[0] = 0.f;
        #pragma unroll
        for (int k = 1; k < 8; ++k) {
            twc[k] = twc[k-1]*c1 - tws[k-1]*s1;
            tws[k] = twc[k-1]*s1 + tws[k-1]*c1;
        }
    }
    // load tile (float4 = 2 complex channels per lane)
    const float4* src4 = (const float4*)buf;
    for (int i = tid; i < 4096; i += 512) {
        int t = i >> 8, h = (i >> 2) & 63, c2 = i & 3;
        float4 v = src4[(((size_t)(t*64 + h)*64 + om)*128 + c0)/2 + c2];
        int pr = LROW(h);
        tre[t][pr][2*c2]   = v.x; tim[t][pr][2*c2]   = v.y;
        tre[t][pr][2*c2+1] = v.z; tim[t][pr][2*c2+1] = v.w;
    }
    __syncthreads();
    int cl = (tid >> 3) & 7, ts = tid >> 6;    // ts in [0,8)
    // H forward stage 1: DFT8 over h1 at fixed h0=d, twiddle w^{-d*k0}
    #pragma unroll
    for (int q = 0; q < 2; ++q) {
        int t = ts*2 + q;
        float2 a[8], Y[8];
        #pragma unroll
        for (int h1 = 0; h1 < 8; ++h1) {
            int pr = LROW(h1*8 + d);
            a[h1] = make_float2(tre[t][pr][cl], tim[t][pr][cl]);
        }
        dft8<-1>(a, Y);
        #pragma unroll
        for (int k0 = 0; k0 < 8; ++k0) {
            int pr = LROW(k0*8 + d);
            tre[t][pr][cl] = Y[k0].x*twc[k0] - Y[k0].y*tws[k0];
            tim[t][pr][cl] = Y[k0].x*tws[k0] + Y[k0].y*twc[k0];
        }
    }
    __syncthreads();
    // H forward stage 2: DFT8 over h0 at fixed k0=d; row k0*8+k1 := bin k0+8*k1
    #pragma unroll
    for (int q = 0; q < 2; ++q) {
        int t = ts*2 + q;
        float2 a[8], Y[8];
        #pragma unroll
        for (int h0 = 0; h0 < 8; ++h0) {
            int pr = LROW(d*8 + h0);
            a[h0] = make_float2(tre[t][pr][cl], tim[t][pr][cl]);
        }
        dft8<-1>(a, Y);
        #pragma unroll
        for (int k1 = 0; k1 < 8; ++k1) {
            int pr = LROW(d*8 + k1);
            tre[t][pr][cl] = Y[k1].x; tim[t][pr][cl] = Y[k1].y;
        }
    }
    __syncthreads();
    // T phase: fwd dft16, G = S(A_f)*B_f multiply, inv dft16 (tables pre-permuted)
    {
        const float CT16[16] = {1.f, 0.9238795325f, 0.7071067812f, 0.3826834324f, 0.f,
                                -0.3826834324f, -0.7071067812f, -0.9238795325f, -1.f,
                                -0.9238795325f, -0.7071067812f, -0.3826834324f, 0.f,
                                0.3826834324f, 0.7071067812f, 0.9238795325f};
        const float ST16[16] = {0.f, 0.3826834324f, 0.7071067812f, 0.9238795325f, 1.f,
                                0.9238795325f, 0.7071067812f, 0.3826834324f, 0.f,
                                -0.3826834324f, -0.7071067812f, -0.9238795325f, -1.f,
                                -0.9238795325f, -0.7071067812f, -0.3826834324f};
        int cg = tid & 7, r = tid >> 3;            // r in [0,64)
        int pr = LROW(r);
        float2 v[16], X[16];
        #pragma unroll
        for (int t = 0; t < 16; ++t) v[t] = make_float2(tre[t][pr][cg], tim[t][pr][cg]);
        dft16<-1>(v, X);
        int kb = (om * 64 + r) * 128 + c0 + cg;    // [kt][om][r][c], kt stride below
        const int PKT = 33 * 64 * 128;
        float2 A0 = Ahw[kb], A1 = Ahw[kb + PKT], A2 = Ahw[kb + 2*PKT];
        float2 B0 = Bhw[kb], B1 = Bhw[kb + PKT], B2 = Bhw[kb + 2*PKT];
        #pragma unroll
        for (int ta = 0; ta < 16; ++ta) {
            float2 wv = make_float2(CT16[ta], -ST16[ta]);
            float2 wc = make_float2(CT16[ta],  ST16[ta]);
            float2 Af = A1; Af = cmac(Af, A0, wc); Af = cmac(Af, A2, wv);
            float2 Bf = B1; Bf = cmac(Bf, B0, wc); Bf = cmac(Bf, B2, wv);
            // S = sum_{k=0}^{7} Af^k = (1+Af)(1+Af^2)(1+Af^4)
            float2 A2q = csq(Af), A4q = csq(A2q);
            float2 S = cmul(make_float2(1.f+Af.x, Af.y), make_float2(1.f+A2q.x, A2q.y));
            S = cmul(S, make_float2(1.f+A4q.x, A4q.y));
            float2 G = cmul(S, Bf);
            X[ta] = cmul(X[ta], G);
        }
        dft16<1>(X, v);
        #pragma unroll
        for (int t = 0; t < 16; ++t) { tre[t][pr][cg] = v[t].x; tim[t][pr][cg] = v[t].y; }
    }
    __syncthreads();
    // inverse H stage 1: DFT8<+1> over eta1 at fixed eta0=d, twiddle w^{+d*h0}
    #pragma unroll
    for (int q = 0; q < 2; ++q) {
        int t = ts*2 + q;
        float2 a[8], Y[8];
        #pragma unroll
        for (int e1 = 0; e1 < 8; ++e1) {
            int pr = LROW(d*8 + e1);
            a[e1] = make_float2(tre[t][pr][cl], tim[t][pr][cl]);
        }
        dft8<1>(a, Y);
        #pragma unroll
        for (int h0 = 0; h0 < 8; ++h0) {
            int pr = LROW(d*8 + h0);
            tre[t][pr][cl] =  Y[h0].x*twc[h0] + Y[h0].y*tws[h0];
            tim[t][pr][cl] = -Y[h0].x*tws[h0] + Y[h0].y*twc[h0];
        }
    }
    __syncthreads();
    // inverse H stage 2: DFT8<+1> over eta0 at fixed h0=d; out row d+8*h1 (natural h)
    #pragma unroll
    for (int q = 0; q < 2; ++q) {
        int t = ts*2 + q;
        float2 a[8], Y[8];
        #pragma unroll
        for (int e0 = 0; e0 < 8; ++e0) {
            int pr = LROW(e0*8 + d);
            a[e0] = make_float2(tre[t][pr][cl], tim[t][pr][cl]);
        }
        dft8<1>(a, Y);
        #pragma unroll
        for (int h1 = 0; h1 < 8; ++h1) {
            int pr = LROW(d + 8*h1);
            tre[t][pr][cl] = Y[h1].x; tim[t][pr][cl] = Y[h1].y;
        }
    }
    __syncthreads();
    // write back (float4)
    float4* dst4 = (float4*)buf;
    for (int i = tid; i < 4096; i += 512) {
        int t = i >> 8, h = (i >> 2) & 63, c2 = i & 3;
        int pr = LROW(h);
        float4 v = make_float4(tre[t][pr][2*c2],   tim[t][pr][2*c2],
                               tre[t][pr][2*c2+1], tim[t][pr][2*c2+1]);
        dst4[(((size_t)(t*64 + h)*64 + om)*128 + c0)/2 + c2] = v;
    }
}

// ------- pass 5: Hermitian-expand + inverse radix-8 FFT along W, real out, scale -------
__global__ __launch_bounds__(256) void p5(const float2* __restrict__ buf,
                                          float* __restrict__ out) {
    __shared__ float tre[64][64];         // 16 KB
    __shared__ float tim[64][64];         // 16 KB
    __shared__ float2 tw64[64];
    int bid = blockIdx.x;
    int chalf = bid & 1, h = (bid >> 1) & 63, t = bid >> 7;
    for (int i = threadIdx.x; i < 64; i += 256) {
        float s, cq; sincosf(6.283185307179586f * i / 64.0f, &s, &cq);
        tw64[i] = make_float2(cq, s);
    }
    const float2* src = buf + (size_t)(t * HH + h) * WW * CC + chalf * 64;
    for (int i = threadIdx.x; i < 33 * 64; i += 256) {
        int om = i >> 6, c = i & 63;
        float2 v = src[(size_t)om * CC + c];
        tre[om][c] = v.x; tim[om][c] = v.y;
        if (om >= 1 && om <= 31) {
            tre[64 - om][c] = v.x; tim[64 - om][c] = -v.y;
        }
    }
    __syncthreads();
    int c = threadIdx.x & 63, s4 = threadIdx.x >> 6;
    #pragma unroll
    for (int g = 0; g < 2; ++g) {
        int h0 = s4 * 2 + g;
        float2 a[8], Y[8];
        #pragma unroll
        for (int h1 = 0; h1 < 8; ++h1)
            a[h1] = make_float2(tre[h1 * 8 + h0][c], tim[h1 * 8 + h0][c]);
        dft8<1>(a, Y);
        #pragma unroll
        for (int k0 = 0; k0 < 8; ++k0) {
            float2 z = cmul(Y[k0], tw64[h0 * k0]);
            tre[k0 * 8 + h0][c] = z.x; tim[k0 * 8 + h0][c] = z.y;
        }
    }
    __syncthreads();
    float* dst = out + (size_t)(t * HH + h) * WW * CC + chalf * 64 + c;
    #pragma unroll
    for (int g = 0; g < 2; ++g) {
        int k0 = s4 * 2 + g;
        float2 b[8], X[8];
        #pragma unroll
        for (int h0 = 0; h0 < 8; ++h0)
            b[h0] = make_float2(tre[k0 * 8 + h0][c], tim[k0 * 8 + h0][c]);
        dft8<1>(b, X);
        #pragma unroll
        for (int k1 = 0; k1 < 8; ++k1)
            dst[(size_t)(k0 + 8 * k1) * CC] = X[k1].x * (1.0f / 65536.0f);
    }
}

extern "C" void kernel_launch(void* const* d_in, const int* in_sizes, int n_in,
                              void* d_out, int out_size, void* d_ws, size_t ws_size,
                              hipStream_t stream) {
    const float* x  = (const float*)d_in[0];
    const float* Ak = (const float*)d_in[1];
    const float* Bk = (const float*)d_in[2];
    float* out = (float*)d_out;

    float2* buf = (float2*)d_ws;                       // 16*64*64*128 float2 (67MB)
    float2* Ahw = buf + (size_t)TT * HH * WW * CC;     // 3*33*64*128 f2 (6.5MB)
    float2* Bhw = Ahw + 3 * 33 * 64 * 128;             // 3*33*64*128 f2 (6.5MB)

    hipLaunchKernelGGL(k_prep, dim3(198),  dim3(256), 0, stream, Ak, Bk, Ahw, Bhw);
    hipLaunchKernelGGL(p1,     dim3(2048), dim3(256), 0, stream, x, buf);
    hipLaunchKernelGGL(pmid,   dim3(528),  dim3(512), 0, stream, buf, Ahw, Bhw);
    hipLaunchKernelGGL(p5,     dim3(2048), dim3(256), 0, stream, buf, out);
}

// Round 5
// 70.260 us; speedup vs baseline: 5.6350x; 1.0918x over previous
//
#include <hip/hip_runtime.h>
#include <hip/hip_fp16.h>
#include <math.h>

#define TT 16
#define HH 64
#define WW 64
#define CC 128

// XOR row swizzle: logical row r -> physical row; keeps stride-8 / block-8
// LDS access patterns at <=2-way bank aliasing with zero padding.
#define LROW(r) (((r) & 0x38) | ((((r) >> 3) ^ (r)) & 7))

__device__ __forceinline__ float2 cadd(float2 a, float2 b){ return make_float2(a.x+b.x, a.y+b.y); }
__device__ __forceinline__ float2 csub(float2 a, float2 b){ return make_float2(a.x-b.x, a.y-b.y); }
__device__ __forceinline__ float2 cmul(float2 a, float2 b) {
    return make_float2(a.x*b.x - a.y*b.y, a.x*b.y + a.y*b.x);
}
__device__ __forceinline__ float2 cmac(float2 acc, float2 a, float2 b) {
    acc.x = fmaf(a.x, b.x, fmaf(-a.y, b.y, acc.x));
    acc.y = fmaf(a.x, b.y, fmaf(a.y, b.x, acc.y));
    return acc;
}
__device__ __forceinline__ float2 csq(float2 a) {
    return make_float2(a.x*a.x - a.y*a.y, 2.f*a.x*a.y);
}

// ---------------- radix butterflies ----------------
template<int SGN>
__device__ __forceinline__ void dft4(float2 b0, float2 b1, float2 b2, float2 b3,
                                     float2& y0, float2& y1, float2& y2, float2& y3) {
    float2 e0 = cadd(b0, b2), e1 = csub(b0, b2);
    float2 o0 = cadd(b1, b3), o1 = csub(b1, b3);
    y0 = cadd(e0, o0); y2 = csub(e0, o0);
    float2 r = make_float2((float)(-SGN) * o1.y, (float)SGN * o1.x);
    y1 = cadd(e1, r); y3 = csub(e1, r);
}

template<int SGN>
__device__ __forceinline__ void dft8(const float2* a, float2* X) {
    const float C = 0.70710678118654752f;
    float2 E0,E1,E2,E3,O0,O1,O2,O3;
    dft4<SGN>(a[0],a[2],a[4],a[6], E0,E1,E2,E3);
    dft4<SGN>(a[1],a[3],a[5],a[7], O0,O1,O2,O3);
    float2 T1 = make_float2(C*(O1.x - (float)SGN*O1.y), C*((float)SGN*O1.x + O1.y));
    float2 T2 = make_float2((float)(-SGN)*O2.y, (float)SGN*O2.x);
    float2 T3 = make_float2(-C*(O3.x + (float)SGN*O3.y), C*((float)SGN*O3.x - O3.y));
    X[0]=cadd(E0,O0); X[4]=csub(E0,O0);
    X[1]=cadd(E1,T1); X[5]=csub(E1,T1);
    X[2]=cadd(E2,T2); X[6]=csub(E2,T2);
    X[3]=cadd(E3,T3); X[7]=csub(E3,T3);
}

template<int SGN>
__device__ __forceinline__ void dft16(const float2* v, float2* X) {
    const float ct[10] = {1.f, 0.92387953251f, 0.70710678119f, 0.38268343236f, 0.f,
                          0.f, -0.70710678119f, 0.f, 0.f, -0.92387953251f};
    const float st[10] = {0.f, 0.38268343236f, 0.70710678119f, 0.92387953251f, 1.f,
                          0.f, 0.70710678119f, 0.f, 0.f, -0.38268343236f};
    float2 Z[16];
    #pragma unroll
    for (int h0 = 0; h0 < 4; ++h0) {
        float2 y0,y1,y2,y3;
        dft4<SGN>(v[h0], v[4+h0], v[8+h0], v[12+h0], y0,y1,y2,y3);
        float2 ys[4] = {y0,y1,y2,y3};
        #pragma unroll
        for (int k0 = 0; k0 < 4; ++k0) {
            int m = h0 * k0;
            float cc = ct[m], ss = (float)SGN * st[m];
            Z[k0*4 + h0] = make_float2(ys[k0].x*cc - ys[k0].y*ss,
                                       ys[k0].x*ss + ys[k0].y*cc);
        }
    }
    #pragma unroll
    for (int k0 = 0; k0 < 4; ++k0) {
        float2 y0,y1,y2,y3;
        dft4<SGN>(Z[k0*4+0], Z[k0*4+1], Z[k0*4+2], Z[k0*4+3], y0,y1,y2,y3);
        X[k0] = y0; X[k0+4] = y1; X[k0+8] = y2; X[k0+12] = y3;
    }
}

// ---------------- fused kernel prep: tanh + kw-DFT + kh-DFT ----------------
__global__ __launch_bounds__(256) void k_prep(const float* __restrict__ Ak,
                                              const float* __restrict__ Bk,
                                              float2* __restrict__ Ahw,
                                              float2* __restrict__ Bhw) {
    __shared__ float Asl[7][7][64];
    __shared__ float Bsl[7][7][64];
    __shared__ float2 Awl[7][64];
    __shared__ float2 Bwl[7][64];
    __shared__ float2 tw64[64];
    int bid = blockIdx.x;
    int kt = bid / 66;
    int rem = bid % 66;
    int om = rem >> 1, chalf = rem & 1;
    int c0 = chalf * 64;
    int tid = threadIdx.x;
    for (int i = tid; i < 64; i += 256) {
        float s, cq; sincosf(-6.283185307179586f * i / 64.0f, &s, &cq);
        tw64[i] = make_float2(cq, s);
    }
    for (int i = tid; i < 49 * 64; i += 256) {
        int p = i >> 6, cl = i & 63;
        int kh = p / 7, kw = p % 7;
        int idx = (((c0 + cl) * 3 + kt) * 7 + kh) * 7 + kw;
        Asl[kh][kw][cl] = 0.9f * tanhf(Ak[idx]);
        Bsl[kh][kw][cl] = Bk[idx];
    }
    __syncthreads();
    for (int i = tid; i < 7 * 64; i += 256) {
        int kh = i >> 6, cl = i & 63;
        float2 aA = make_float2(0.f,0.f), aB = make_float2(0.f,0.f);
        #pragma unroll
        for (int kw = 0; kw < 7; ++kw) {
            float2 t = tw64[(om * (kw - 3)) & 63];
            float va = Asl[kh][kw][cl], vb = Bsl[kh][kw][cl];
            aA.x = fmaf(va, t.x, aA.x); aA.y = fmaf(va, t.y, aA.y);
            aB.x = fmaf(vb, t.x, aB.x); aB.y = fmaf(vb, t.y, aB.y);
        }
        Awl[kh][cl] = aA; Bwl[kh][cl] = aB;
    }
    __syncthreads();
    for (int i = tid; i < 64 * 64; i += 256) {
        int eta = i >> 6, cl = i & 63;
        float2 aA = make_float2(0.f,0.f), aB = make_float2(0.f,0.f);
        #pragma unroll
        for (int kh = 0; kh < 7; ++kh) {
            float2 t = tw64[(eta * (kh - 3)) & 63];
            aA = cmac(aA, Awl[kh][cl], t);
            aB = cmac(aB, Bwl[kh][cl], t);
        }
        int ep = ((eta & 7) << 3) | (eta >> 3);      // digit-swapped eta position
        int o = ((kt * 33 + om) * 64 + ep) * 128 + c0 + cl;
        Ahw[o] = aA; Bhw[o] = aB;
    }
}

// ------- pass 1: forward radix-8 FFT along W (real input), write omega<=32 as half2 -------
__global__ __launch_bounds__(256) void p1(const float* __restrict__ x,
                                          __half2* __restrict__ bufh) {
    __shared__ float rf[64][64];          // input real, then stage-1 re
    __shared__ float zim[64][64];         // stage-1 im
    __shared__ float2 tw64[64];
    int bid = blockIdx.x;
    int chalf = bid & 1, h = (bid >> 1) & 63, t = bid >> 7;
    for (int i = threadIdx.x; i < 64; i += 256) {
        float s, cq; sincosf(-6.283185307179586f * i / 64.0f, &s, &cq);
        tw64[i] = make_float2(cq, s);
    }
    const float4* src4 = (const float4*)(x + (size_t)(t * HH + h) * WW * CC + chalf * 64);
    for (int i = threadIdx.x; i < 1024; i += 256) {
        int w = i >> 4, c4 = i & 15;
        float4 v = src4[w * 32 + c4];
        rf[w][c4*4+0] = v.x; rf[w][c4*4+1] = v.y;
        rf[w][c4*4+2] = v.z; rf[w][c4*4+3] = v.w;
    }
    __syncthreads();
    int c = threadIdx.x & 63, s4 = threadIdx.x >> 6;
    #pragma unroll
    for (int g = 0; g < 2; ++g) {
        int h0 = s4 * 2 + g;
        float2 a[8], Y[8];
        #pragma unroll
        for (int h1 = 0; h1 < 8; ++h1) a[h1] = make_float2(rf[h1 * 8 + h0][c], 0.f);
        dft8<-1>(a, Y);
        #pragma unroll
        for (int k0 = 0; k0 < 8; ++k0) {
            float2 z = cmul(Y[k0], tw64[h0 * k0]);
            rf[k0 * 8 + h0][c] = z.x; zim[k0 * 8 + h0][c] = z.y;
        }
    }
    __syncthreads();
    __half2* dst = bufh + (size_t)(t * HH + h) * WW * CC + chalf * 64 + c;
    #pragma unroll
    for (int g = 0; g < 2; ++g) {
        int k0 = s4 * 2 + g;
        float2 b[8], X[8];
        #pragma unroll
        for (int h0 = 0; h0 < 8; ++h0)
            b[h0] = make_float2(rf[k0 * 8 + h0][c], zim[k0 * 8 + h0][c]);
        dft8<-1>(b, X);
        #pragma unroll
        for (int k1 = 0; k1 < 8; ++k1) {
            int om = k0 + 8 * k1;
            if (om <= 32) dst[(size_t)om * CC] = __float22half2_rn(X[k1]);
        }
    }
}

// ------- fused middle pass: H-FFT + T-FFT + G multiply + inv-T + inv-H, in place -------
// 256 threads, one block per (omega in [0..32], 4-channel chunk). 32KB LDS SoA tile.
__global__ __launch_bounds__(256, 4) void pmid(__half2* __restrict__ bufh,
                                               const float2* __restrict__ Ahw,
                                               const float2* __restrict__ Bhw) {
    __shared__ float tre[16][64][4];      // 16 KB
    __shared__ float tim[16][64][4];      // 16 KB
    // XCD-chunked swizzle: 1056 = 8*132
    int l = (blockIdx.x & 7) * 132 + (blockIdx.x >> 3);
    int om = l >> 5, cc = l & 31;
    int c0 = cc * 4;
    int tid = threadIdx.x;

    // prefetch G tables into registers (independent loads, hidden under H stages)
    int cg = tid & 3, rT = tid >> 2;                 // T-phase mapping
    const int PKT = 33 * 64 * 128;
    int kb = (om * 64 + rT) * 128 + c0 + cg;
    float2 A0 = Ahw[kb], A1 = Ahw[kb + PKT], A2 = Ahw[kb + 2*PKT];
    float2 B0 = Bhw[kb], B1 = Bhw[kb + PKT], B2 = Bhw[kb + 2*PKT];

    int d = tid & 7;
    float twc[8], tws[8];
    {
        float s1, c1; sincosf(-6.283185307179586f * d / 64.0f, &s1, &c1);
        twc[0] = 1.f; tws[0] = 0.f;
        #pragma unroll
        for (int k = 1; k < 8; ++k) {
            twc[k] = twc[k-1]*c1 - tws[k-1]*s1;
            tws[k] = twc[k-1]*s1 + tws[k-1]*c1;
        }
    }
    // load tile (2 half2 = 2 complex = 8B per lane-iter)
    for (int i = tid; i < 2048; i += 256) {
        int t = i >> 7, h = (i >> 1) & 63, p = i & 1;
        size_t e = ((size_t)((t*64 + h)*64 + om))*128 + c0 + 2*p;
        __half2 ha = bufh[e], hb = bufh[e+1];
        float2 v0 = __half22float2(ha), v1 = __half22float2(hb);
        int pr = LROW(h);
        tre[t][pr][2*p]   = v0.x; tim[t][pr][2*p]   = v0.y;
        tre[t][pr][2*p+1] = v1.x; tim[t][pr][2*p+1] = v1.y;
    }
    __syncthreads();
    int cl = (tid >> 3) & 3, ts = tid >> 5;          // ts in [0,8)
    // H forward stage 1: DFT8 over h1 at fixed h0=d, twiddle w^{-d*k0}
    #pragma unroll
    for (int q = 0; q < 2; ++q) {
        int t = ts*2 + q;
        float2 a[8], Y[8];
        #pragma unroll
        for (int h1 = 0; h1 < 8; ++h1) {
            int pr = LROW(h1*8 + d);
            a[h1] = make_float2(tre[t][pr][cl], tim[t][pr][cl]);
        }
        dft8<-1>(a, Y);
        #pragma unroll
        for (int k0 = 0; k0 < 8; ++k0) {
            int pr = LROW(k0*8 + d);
            tre[t][pr][cl] = Y[k0].x*twc[k0] - Y[k0].y*tws[k0];
            tim[t][pr][cl] = Y[k0].x*tws[k0] + Y[k0].y*twc[k0];
        }
    }
    __syncthreads();
    // H forward stage 2: DFT8 over h0 at fixed k0=d; row k0*8+k1 := bin k0+8*k1
    #pragma unroll
    for (int q = 0; q < 2; ++q) {
        int t = ts*2 + q;
        float2 a[8], Y[8];
        #pragma unroll
        for (int h0 = 0; h0 < 8; ++h0) {
            int pr = LROW(d*8 + h0);
            a[h0] = make_float2(tre[t][pr][cl], tim[t][pr][cl]);
        }
        dft8<-1>(a, Y);
        #pragma unroll
        for (int k1 = 0; k1 < 8; ++k1) {
            int pr = LROW(d*8 + k1);
            tre[t][pr][cl] = Y[k1].x; tim[t][pr][cl] = Y[k1].y;
        }
    }
    __syncthreads();
    // T phase: fwd dft16, G = S(A_f)*B_f multiply, inv dft16 (tables pre-permuted)
    {
        const float CT16[16] = {1.f, 0.9238795325f, 0.7071067812f, 0.3826834324f, 0.f,
                                -0.3826834324f, -0.7071067812f, -0.9238795325f, -1.f,
                                -0.9238795325f, -0.7071067812f, -0.3826834324f, 0.f,
                                0.3826834324f, 0.7071067812f, 0.9238795325f};
        const float ST16[16] = {0.f, 0.3826834324f, 0.7071067812f, 0.9238795325f, 1.f,
                                0.9238795325f, 0.7071067812f, 0.3826834324f, 0.f,
                                -0.3826834324f, -0.7071067812f, -0.9238795325f, -1.f,
                                -0.9238795325f, -0.7071067812f, -0.3826834324f};
        int pr = LROW(rT);
        float2 v[16], X[16];
        #pragma unroll
        for (int t = 0; t < 16; ++t) v[t] = make_float2(tre[t][pr][cg], tim[t][pr][cg]);
        dft16<-1>(v, X);
        #pragma unroll
        for (int ta = 0; ta < 16; ++ta) {
            float2 wv = make_float2(CT16[ta], -ST16[ta]);
            float2 wc = make_float2(CT16[ta],  ST16[ta]);
            float2 Af = A1; Af = cmac(Af, A0, wc); Af = cmac(Af, A2, wv);
            float2 Bf = B1; Bf = cmac(Bf, B0, wc); Bf = cmac(Bf, B2, wv);
            // S = sum_{k=0}^{7} Af^k = (1+Af)(1+Af^2)(1+Af^4)
            float2 A2q = csq(Af), A4q = csq(A2q);
            float2 S = cmul(make_float2(1.f+Af.x, Af.y), make_float2(1.f+A2q.x, A2q.y));
            S = cmul(S, make_float2(1.f+A4q.x, A4q.y));
            float2 G = cmul(S, Bf);
            X[ta] = cmul(X[ta], G);
        }
        dft16<1>(X, v);
        #pragma unroll
        for (int t = 0; t < 16; ++t) { tre[t][pr][cg] = v[t].x; tim[t][pr][cg] = v[t].y; }
    }
    __syncthreads();
    // inverse H stage 1: DFT8<+1> over eta1 at fixed eta0=d, twiddle w^{+d*h0}
    #pragma unroll
    for (int q = 0; q < 2; ++q) {
        int t = ts*2 + q;
        float2 a[8], Y[8];
        #pragma unroll
        for (int e1 = 0; e1 < 8; ++e1) {
            int pr = LROW(d*8 + e1);
            a[e1] = make_float2(tre[t][pr][cl], tim[t][pr][cl]);
        }
        dft8<1>(a, Y);
        #pragma unroll
        for (int h0 = 0; h0 < 8; ++h0) {
            int pr = LROW(d*8 + h0);
            tre[t][pr][cl] =  Y[h0].x*twc[h0] + Y[h0].y*tws[h0];
            tim[t][pr][cl] = -Y[h0].x*tws[h0] + Y[h0].y*twc[h0];
        }
    }
    __syncthreads();
    // inverse H stage 2: DFT8<+1> over eta0 at fixed h0=d; out row d+8*h1 (natural h)
    #pragma unroll
    for (int q = 0; q < 2; ++q) {
        int t = ts*2 + q;
        float2 a[8], Y[8];
        #pragma unroll
        for (int e0 = 0; e0 < 8; ++e0) {
            int pr = LROW(e0*8 + d);
            a[e0] = make_float2(tre[t][pr][cl], tim[t][pr][cl]);
        }
        dft8<1>(a, Y);
        #pragma unroll
        for (int h1 = 0; h1 < 8; ++h1) {
            int pr = LROW(d + 8*h1);
            tre[t][pr][cl] = Y[h1].x; tim[t][pr][cl] = Y[h1].y;
        }
    }
    __syncthreads();
    // write back with 1/64 fold (keeps half-range small; p5 applies 1/1024)
    for (int i = tid; i < 2048; i += 256) {
        int t = i >> 7, h = (i >> 1) & 63, p = i & 1;
        int pr = LROW(h);
        size_t e = ((size_t)((t*64 + h)*64 + om))*128 + c0 + 2*p;
        bufh[e]   = __float22half2_rn(make_float2(tre[t][pr][2*p]   * 0.015625f,
                                                  tim[t][pr][2*p]   * 0.015625f));
        bufh[e+1] = __float22half2_rn(make_float2(tre[t][pr][2*p+1] * 0.015625f,
                                                  tim[t][pr][2*p+1] * 0.015625f));
    }
}

// ------- pass 5: Hermitian-expand + inverse radix-8 FFT along W, real out, scale -------
__global__ __launch_bounds__(256) void p5(const __half2* __restrict__ bufh,
                                          float* __restrict__ out) {
    __shared__ float tre[64][64];
    __shared__ float tim[64][64];
    __shared__ float2 tw64[64];
    int bid = blockIdx.x;
    int chalf = bid & 1, h = (bid >> 1) & 63, t = bid >> 7;
    for (int i = threadIdx.x; i < 64; i += 256) {
        float s, cq; sincosf(6.283185307179586f * i / 64.0f, &s, &cq);
        tw64[i] = make_float2(cq, s);
    }
    const __half2* src = bufh + (size_t)(t * HH + h) * WW * CC + chalf * 64;
    for (int i = threadIdx.x; i < 33 * 64; i += 256) {
        int om = i >> 6, c = i & 63;
        float2 v = __half22float2(src[(size_t)om * CC + c]);
        tre[om][c] = v.x; tim[om][c] = v.y;
        if (om >= 1 && om <= 31) {
            tre[64 - om][c] = v.x; tim[64 - om][c] = -v.y;
        }
    }
    __syncthreads();
    int c = threadIdx.x & 63, s4 = threadIdx.x >> 6;
    #pragma unroll
    for (int g = 0; g < 2; ++g) {
        int h0 = s4 * 2 + g;
        float2 a[8], Y[8];
        #pragma unroll
        for (int h1 = 0; h1 < 8; ++h1)
            a[h1] = make_float2(tre[h1 * 8 + h0][c], tim[h1 * 8 + h0][c]);
        dft8<1>(a, Y);
        #pragma unroll
        for (int k0 = 0; k0 < 8; ++k0) {
            float2 z = cmul(Y[k0], tw64[h0 * k0]);
            tre[k0 * 8 + h0][c] = z.x; tim[k0 * 8 + h0][c] = z.y;
        }
    }
    __syncthreads();
    float* dst = out + (size_t)(t * HH + h) * WW * CC + chalf * 64 + c;
    #pragma unroll
    for (int g = 0; g < 2; ++g) {
        int k0 = s4 * 2 + g;
        float2 b[8], X[8];
        #pragma unroll
        for (int h0 = 0; h0 < 8; ++h0)
            b[h0] = make_float2(tre[k0 * 8 + h0][c], tim[k0 * 8 + h0][c]);
        dft8<1>(b, X);
        #pragma unroll
        for (int k1 = 0; k1 < 8; ++k1)
            dst[(size_t)(k0 + 8 * k1) * CC] = X[k1].x * (1.0f / 1024.0f);
    }
}

extern "C" void kernel_launch(void* const* d_in, const int* in_sizes, int n_in,
                              void* d_out, int out_size, void* d_ws, size_t ws_size,
                              hipStream_t stream) {
    const float* x  = (const float*)d_in[0];
    const float* Ak = (const float*)d_in[1];
    const float* Bk = (const float*)d_in[2];
    float* out = (float*)d_out;

    __half2* bufh = (__half2*)d_ws;                          // 8.39M half2 (33.5MB)
    float2* Ahw = (float2*)(bufh + (size_t)TT * HH * WW * CC);
    float2* Bhw = Ahw + 3 * 33 * 64 * 128;                   // 6.5MB each

    hipLaunchKernelGGL(k_prep, dim3(198),  dim3(256), 0, stream, Ak, Bk, Ahw, Bhw);
    hipLaunchKernelGGL(p1,     dim3(2048), dim3(256), 0, stream, x, bufh);
    hipLaunchKernelGGL(pmid,   dim3(1056), dim3(256), 0, stream, bufh, Ahw, Bhw);
    hipLaunchKernelGGL(p5,     dim3(2048), dim3(256), 0, stream, bufh, out);
}